// Round 2
// baseline (593.865 us; speedup 1.0000x reference)
//
#include <hip/hip_runtime.h>

typedef _Float16 f16x8 __attribute__((ext_vector_type(8)));
typedef _Float16 f16x2 __attribute__((ext_vector_type(2)));
typedef float    f32x4 __attribute__((ext_vector_type(4)));

#define CIN    16
#define COUT   64
#define H      256
#define W      256
#define OH     254
#define OW     254
#define TH     32
#define TW     32
#define NT     2                       // vertical tiles per block
#define IN_H   (TH + 2)
#define IN_W   (TW + 2)
#define IN_PIX (IN_H * IN_W)
#define NU     (IN_H * 8 * 9)          // 2448 staging units per tile

// weight redistribution scratch (overlaid on xs, consumed before x staging):
// layout [tap 0..9][cout 0..63][cin 0..23], cin 16..23 = pad (never read),
// tap 9 = zero pad row (read by the s=4,qh=1 fragments -> zero weights).
#define WSTRIDE 24
#define WTAPSZ  (COUT * WSTRIDE)       // 1536 f16

// tanh(x) = 1 - 2/(e^{2x}+1): robust at +-inf
__device__ __forceinline__ float ftanh(float x) {
  float e = __expf(x + x);
  float r = __builtin_amdgcn_rcpf(e + 1.0f);
  return 1.0f - (r + r);
}

__device__ __forceinline__ f32x4 vmin4(f32x4 a, f32x4 b) {
  f32x4 r;
  r[0] = fminf(a[0], b[0]); r[1] = fminf(a[1], b[1]);
  r[2] = fminf(a[2], b[2]); r[3] = fminf(a[3], b[3]);
  return r;
}

__global__ __launch_bounds__(256, 4)
void conv_min_tanh_mfma(const float* __restrict__ x, const float* __restrict__ wgt,
                        const float* __restrict__ bias, float* __restrict__ out) {
  // input tile, fp16, interleaved [pixel][cin]: 34*34*16*2 = 36,992 B
  __shared__ __align__(16) _Float16 xs[IN_PIX * CIN];

  const int t    = threadIdx.x;
  const int b    = blockIdx.z;
  const int ow0  = blockIdx.x * TW;
  const int oh0b = blockIdx.y * (TH * NT);   // strip base (2 tiles tall)

  const int lane = t & 63;
  const int ln   = lane & 15;
  const int q    = lane >> 4;
  const int qh   = q >> 1;
  const int ql   = q & 1;

  // ---- weight phase (ONCE per block, amortized over NT tiles) ----
  // coalesced dwordx4 loads -> f16 scatter into xs-scratch
  {
    _Float16* ws = xs;
    const f32x4* w4 = (const f32x4*)wgt;   // 9216 floats total, 36/thread
#pragma unroll
    for (int k = 0; k < 9; ++k) {
      const f32x4 v = w4[9 * t + k];
#pragma unroll
      for (int e = 0; e < 4; ++e) {
        const int g   = (9 * t + k) * 4 + e;   // index into [cout][cin][tap]
        const int co  = g / 144;
        const int r   = g - 144 * co;
        const int ci  = r / 9;
        const int tap = r - 9 * ci;
        ws[(tap * COUT + co) * WSTRIDE + ci] = (_Float16)v[e];
      }
    }
    // zero the tap-9 pad row: 3072 B = 768 dwords
    uint32_t* wz = (uint32_t*)(ws + 9 * WTAPSZ);
    wz[t] = 0u; wz[t + 256] = 0u; wz[t + 512] = 0u;
  }
  __syncthreads();

  // ---- per-lane A-fragments via ds_read_b128 (16B aligned) ----
  // A[m=cout][k], lane holds cout = mt*16+ln, k = s*32 + q*8 + j,
  // K order: k = tap*16 + cin (tap = kh*3+kw), tap 9 zero-padded.
  // NOTE: wf = 20 frags = 80 regs (AGPR side of the unified file) --
  // this is the occupancy limiter (~3 waves/SIMD).
  f16x8 wf[5][4];
  {
    const _Float16* ws = xs;
#pragma unroll
    for (int s = 0; s < 5; ++s) {
      const int tap = 2 * s + qh;            // 0..9
#pragma unroll
      for (int mt = 0; mt < 4; ++mt) {
        const int cout = mt * 16 + ln;
        wf[s][mt] = *(const f16x8*)(&ws[(tap * COUT + cout) * WSTRIDE + ql * 8]);
      }
    }
  }
  // (sync deferred: tile-0 staging preps are reg-only and issued first,
  //  so the barrier below both protects ws->xs reuse AND hides HBM latency)

  // per-lane LDS element offset per K-step (tap clamped to 8; its weights are 0)
  int xoff[5];
#pragma unroll
  for (int s = 0; s < 5; ++s) {
    int tap = 2 * s + qh;
    if (tap > 8) tap = 8;
    const int kh = tap / 3;
    const int kw = tap - kh * 3;
    xoff[s] = (kh * IN_W + kw) * CIN + ql * 8;
  }

  // bias folded into acc init: C/D row = q*4 + reg -> cout = mt*16 + q*4 + r
  f32x4 binit[4];
#pragma unroll
  for (int mt = 0; mt < 4; ++mt)
#pragma unroll
    for (int r = 0; r < 4; ++r)
      binit[mt][r] = bias[mt * 16 + q * 4 + r];

  // ---- staging state: 4-deep software pipeline (all indices static) ----
  f32x4 sv0[4], sv1[4];
  int   sbase[4], sj[4];
  bool  sact[4];

  const int wv = t >> 6;

  for (int ti = 0; ti < NT; ++ti) {
    const int oh0 = oh0b + ti * TH;

    // prep(i, slot): issue global loads for staging unit batch i (regs only)
    auto prep = [&](int i, int slot) {
      const int  u   = t + 256 * i;
      const bool act = (u < NU);
      const int  s   = u / 9;
      const int  j   = u - 9 * s;
      const int  row = s >> 3;
      const int  cp  = s & 7;
      const int  ih  = oh0 + row;
      const int  iw0 = ow0 + 4 * j;
      const f32x4 z = {0.f, 0.f, 0.f, 0.f};
      sv0[slot] = z; sv1[slot] = z;
      if (act && ih < H && iw0 + 3 < W) {
        const float* p = x + (((size_t)b * CIN + 2 * cp) * H + ih) * W + iw0;
        sv0[slot] = *(const f32x4*)p;
        sv1[slot] = *(const f32x4*)(p + H * W);
      }
      sbase[slot] = (row * IN_W + 4 * j) * CIN + 2 * cp;
      sj[slot]    = j;
      sact[slot]  = act;
    };
    auto flush = [&](int slot) {
      if (sact[slot]) {
        const int base = sbase[slot];
        const int j    = sj[slot];
#pragma unroll
        for (int e = 0; e < 4; ++e) {
          if (4 * j + e < IN_W) {  // drop cols 34,35 of the j==8 over-read
            f16x2 h;
            h[0] = (_Float16)sv0[slot][e];
            h[1] = (_Float16)sv1[slot][e];
            *(f16x2*)(&xs[base + e * CIN]) = h;
          }
        }
      }
    };

    // issue first 4 batches BEFORE the barrier: HBM latency hides under the
    // barrier wait (tile 0: under weight-frag reads; tile 1: compute drain)
#pragma unroll
    for (int p = 0; p < 4; ++p) prep(p, p);
    __syncthreads();   // ti==0: ws frag reads done; ti>0: xs compute reads done

    // drain/refill: flush(i) waits only slot-i loads; 3 batches stay in flight
#pragma unroll
    for (int i = 0; i < 10; ++i) {
      flush(i & 3);
      if (i + 4 < 10) prep(i + 4, (i + 4) & 3);
    }
    __syncthreads();

    // ---- compute: each wave does 8 rows x 2 col-tiles of 16 pixels ----
    for (int rr = 0; rr < 8; ++rr) {
      const int row = wv * 8 + rr;
#pragma unroll
      for (int ct = 0; ct < 2; ++ct) {
        const int base_idx = (row * IN_W + ct * 16 + ln) * CIN;
        f32x4 a0 = binit[0], a1 = binit[1], a2 = binit[2], a3 = binit[3];
#pragma unroll
        for (int s = 0; s < 5; ++s) {
          f16x8 xf = *(const f16x8*)(&xs[base_idx + xoff[s]]);  // ds_read_b128
          a0 = __builtin_amdgcn_mfma_f32_16x16x32_f16(wf[s][0], xf, a0, 0, 0, 0);
          a1 = __builtin_amdgcn_mfma_f32_16x16x32_f16(wf[s][1], xf, a1, 0, 0, 0);
          a2 = __builtin_amdgcn_mfma_f32_16x16x32_f16(wf[s][2], xf, a2, 0, 0, 0);
          a3 = __builtin_amdgcn_mfma_f32_16x16x32_f16(wf[s][3], xf, a3, 0, 0, 0);
        }
        // min over 64 couts: 4 m-tiles x 4 regs in-lane, then across quads
        f32x4 m4 = vmin4(vmin4(a0, a1), vmin4(a2, a3));
        float v = fminf(fminf(m4[0], m4[1]), fminf(m4[2], m4[3]));
        v = fminf(v, __shfl_xor(v, 16));
        v = fminf(v, __shfl_xor(v, 32));
        v = ftanh(ftanh(v));
        const int oh = oh0 + row;
        const int ow = ow0 + ct * 16 + ln;
        if (q == 0 && oh < OH && ow < OW)
          out[((size_t)b * OH + oh) * OW + ow] = v;   // 16 lanes, 64B coalesced
      }
    }
  }
}

extern "C" void kernel_launch(void* const* d_in, const int* in_sizes, int n_in,
                              void* d_out, int out_size, void* d_ws, size_t ws_size,
                              hipStream_t stream) {
  const float* x    = (const float*)d_in[0];
  const float* wgt  = (const float*)d_in[1];  // [64][16][3][3]
  const float* bias = (const float*)d_in[2];  // [64]
  float* out = (float*)d_out;                 // [64][1][254][254]
  dim3 grid((OW + TW - 1) / TW, OH / (TH * NT) + 1, 64);  // 8 x 4 x 64
  conv_min_tanh_mfma<<<grid, 256, 0, stream>>>(x, wgt, bias, out);
}

// Round 3
// 411.705 us; speedup vs baseline: 1.4425x; 1.4425x over previous
//
#include <hip/hip_runtime.h>

typedef _Float16 f16x8 __attribute__((ext_vector_type(8)));
typedef _Float16 f16x2 __attribute__((ext_vector_type(2)));
typedef float    f32x4 __attribute__((ext_vector_type(4)));

#define CIN    16
#define COUT   64
#define H      256
#define W      256
#define OH     254
#define OW     254
#define TH     32
#define TW     32
#define IN_H   (TH + 2)
#define IN_W   (TW + 2)
#define IN_PIX (IN_H * IN_W)
#define NU     (IN_H * 8 * 9)          // 2448 staging units

// tanh(x) = 1 - 2/(e^{2x}+1): robust at +-inf
__device__ __forceinline__ float ftanh(float x) {
  float e = __expf(x + x);
  float r = __builtin_amdgcn_rcpf(e + 1.0f);
  return 1.0f - (r + r);
}

__device__ __forceinline__ f32x4 vmin4(f32x4 a, f32x4 b) {
  f32x4 r;
  r[0] = fminf(a[0], b[0]); r[1] = fminf(a[1], b[1]);
  r[2] = fminf(a[2], b[2]); r[3] = fminf(a[3], b[3]);
  return r;
}

// ---- one-time weight redistribution into workspace ----
// layout: [tap 0..9][cout 0..63][ci 0..15] f16, tap 9 = zeros.
// A-fragment for (s, qh, ql, mt, ln) is then a single aligned 16B load at
// ((2s+qh)*64 + mt*16+ln)*16 + ql*8.  Total 20 KB, L2-resident for main.
__global__ __launch_bounds__(256, 1)
void weight_prep(const float* __restrict__ wgt, _Float16* __restrict__ ws) {
  const int t = threadIdx.x;
  // zero tap-9 pad row: 64*16 f16 = 512 dwords
  uint32_t* wz = (uint32_t*)(ws + 9 * COUT * 16);
  wz[t] = 0u; wz[t + 256] = 0u;
  // coalesced dwordx4 read of [cout][cin][tap] f32, scatter-store as f16
  const f32x4* w4 = (const f32x4*)wgt;   // 9216 floats, 36 per thread
#pragma unroll
  for (int k = 0; k < 9; ++k) {
    const f32x4 v = w4[9 * t + k];
#pragma unroll
    for (int e = 0; e < 4; ++e) {
      const int g   = (9 * t + k) * 4 + e;
      const int co  = g / 144;
      const int r   = g - 144 * co;
      const int ci  = r / 9;
      const int tap = r - 9 * ci;
      ws[(tap * COUT + co) * 16 + ci] = (_Float16)v[e];
    }
  }
}

__global__ __launch_bounds__(256, 4)
void conv_min_tanh_mfma(const float* __restrict__ x, const _Float16* __restrict__ ws,
                        const float* __restrict__ bias, float* __restrict__ out) {
  // input tile, fp16, interleaved [pixel][cin]: 34*34*16*2 = 36,992 B
  __shared__ __align__(16) _Float16 xs[IN_PIX * CIN];

  const int t   = threadIdx.x;
  const int b   = blockIdx.z;
  const int ow0 = blockIdx.x * TW;
  const int oh0 = blockIdx.y * TH;

  const int lane = t & 63;
  const int ln   = lane & 15;
  const int q    = lane >> 4;
  const int qh   = q >> 1;
  const int ql   = q & 1;

  // ---- A-fragments: 20 x 16B global loads, L2-broadcast (same 20KB for all
  // blocks). A[m=cout][k], lane holds cout = mt*16+ln, k = s*32 + q*8 + j,
  // K order: k = tap*16 + cin (tap = kh*3+kw), tap 9 reads the zero row.
  f16x8 wf[5][4];
#pragma unroll
  for (int s = 0; s < 5; ++s) {
    const int tap = 2 * s + qh;            // 0..9
#pragma unroll
    for (int mt = 0; mt < 4; ++mt) {
      const int cout = mt * 16 + ln;
      wf[s][mt] = *(const f16x8*)(ws + (tap * COUT + cout) * 16 + ql * 8);
    }
  }

  // ---- stage input tile, 2-deep software-pipelined ----
  // unit u = (row 0..33, chpair 0..7, j 0..8); lane loads 4 consecutive
  // pixels for channels 2cp,2cp+1 (two dwordx4), packs 4 f16x2 -> LDS.
  {
    f32x4 sv0[2], sv1[2];
    int   sbase[2], sj[2];
    bool  sact[2];

    auto prep = [&](int i, int slot) {
      const int  u   = t + 256 * i;
      const bool act = (u < NU);
      const int  s   = u / 9;
      const int  j   = u - 9 * s;
      const int  row = s >> 3;
      const int  cp  = s & 7;
      const int  ih  = oh0 + row;
      const int  iw0 = ow0 + 4 * j;
      const f32x4 z = {0.f, 0.f, 0.f, 0.f};
      sv0[slot] = z; sv1[slot] = z;
      if (act && ih < H && iw0 + 3 < W) {
        const float* p = x + (((size_t)b * CIN + 2 * cp) * H + ih) * W + iw0;
        sv0[slot] = *(const f32x4*)p;
        sv1[slot] = *(const f32x4*)(p + H * W);
      }
      sbase[slot] = (row * IN_W + 4 * j) * CIN + 2 * cp;
      sj[slot]    = j;
      sact[slot]  = act;
    };
    auto flush = [&](int slot) {
      if (sact[slot]) {
        const int base = sbase[slot];
        const int j    = sj[slot];
#pragma unroll
        for (int e = 0; e < 4; ++e) {
          if (4 * j + e < IN_W) {  // drop cols 34,35 of the j==8 over-read
            f16x2 h;
            h[0] = (_Float16)sv0[slot][e];
            h[1] = (_Float16)sv1[slot][e];
            *(f16x2*)(&xs[base + e * CIN]) = h;
          }
        }
      }
    };

    prep(0, 0);
#pragma unroll
    for (int i = 0; i < 10; ++i) {
      if (i < 9) prep(i + 1, (i + 1) & 1);   // issue next loads first
      flush(i & 1);                           // then drain current
    }
  }

  // per-lane LDS element offset per K-step (tap clamped to 8; its weights are 0)
  int xoff[5];
#pragma unroll
  for (int s = 0; s < 5; ++s) {
    int tap = 2 * s + qh;
    if (tap > 8) tap = 8;
    const int kh = tap / 3;
    const int kw = tap - kh * 3;
    xoff[s] = (kh * IN_W + kw) * CIN + ql * 8;
  }

  // bias folded into acc init: C/D row = q*4 + reg -> cout = mt*16 + q*4 + r
  f32x4 binit[4];
#pragma unroll
  for (int mt = 0; mt < 4; ++mt)
#pragma unroll
    for (int r = 0; r < 4; ++r)
      binit[mt][r] = bias[mt * 16 + q * 4 + r];

  __syncthreads();   // the only barrier: xs staged, compute may read

  // ---- main: each wave does 8 rows x 2 col-tiles of 16 pixels ----
  const int wv = t >> 6;
  for (int rr = 0; rr < 8; ++rr) {
    const int row = wv * 8 + rr;
#pragma unroll
    for (int ct = 0; ct < 2; ++ct) {
      const int base_idx = (row * IN_W + ct * 16 + ln) * CIN;
      f32x4 a0 = binit[0], a1 = binit[1], a2 = binit[2], a3 = binit[3];
#pragma unroll
      for (int s = 0; s < 5; ++s) {
        f16x8 xf = *(const f16x8*)(&xs[base_idx + xoff[s]]);  // ds_read_b128
        a0 = __builtin_amdgcn_mfma_f32_16x16x32_f16(wf[s][0], xf, a0, 0, 0, 0);
        a1 = __builtin_amdgcn_mfma_f32_16x16x32_f16(wf[s][1], xf, a1, 0, 0, 0);
        a2 = __builtin_amdgcn_mfma_f32_16x16x32_f16(wf[s][2], xf, a2, 0, 0, 0);
        a3 = __builtin_amdgcn_mfma_f32_16x16x32_f16(wf[s][3], xf, a3, 0, 0, 0);
      }
      // min over 64 couts: 4 m-tiles x 4 regs in-lane, then across quads
      f32x4 m4 = vmin4(vmin4(a0, a1), vmin4(a2, a3));
      float v = fminf(fminf(m4[0], m4[1]), fminf(m4[2], m4[3]));
      v = fminf(v, __shfl_xor(v, 16));
      v = fminf(v, __shfl_xor(v, 32));
      v = ftanh(ftanh(v));
      const int oh = oh0 + row;
      const int ow = ow0 + ct * 16 + ln;
      if (q == 0 && oh < OH && ow < OW)
        out[((size_t)b * OH + oh) * OW + ow] = v;   // 16 lanes, 64B coalesced
    }
  }
}

extern "C" void kernel_launch(void* const* d_in, const int* in_sizes, int n_in,
                              void* d_out, int out_size, void* d_ws, size_t ws_size,
                              hipStream_t stream) {
  const float* x    = (const float*)d_in[0];
  const float* wgt  = (const float*)d_in[1];  // [64][16][3][3]
  const float* bias = (const float*)d_in[2];  // [64]
  float* out = (float*)d_out;                 // [64][1][254][254]
  _Float16* ws = (_Float16*)d_ws;             // 10*64*16 f16 = 20,480 B

  weight_prep<<<dim3(1, 1, 1), 256, 0, stream>>>(wgt, ws);
  dim3 grid((OW + TW - 1) / TW, (OH + TH - 1) / TH, 64);  // 8 x 8 x 64
  conv_min_tanh_mfma<<<grid, 256, 0, stream>>>(x, ws, bias, out);
}